// Round 17
// baseline (390.058 us; speedup 1.0000x reference)
//
#include <hip/hip_runtime.h>

#define N_NODES 50000
#define N_EDGES 800000
#define N_META 3
#define IN_DIM 256
#define HD 128
#define HEADS 8
#define HID 16
#define OUT_DIM 8
#define NBKT 196          // ceil(50000/256) coarse buckets; == #4096-edge tiles
#define BCAP 5120         // padded bucket capacity (mean 4096, +16 sigma)
#define TILE_E 4096       // edges per bin block
#define NUMPAD 2064       // per-meta padded accum: 128 cols * 16 floats + den
#define GEMM_BX ((N_NODES + 63) / 64)           // 782
#define ELER_BX ((N_NODES * HEADS + 255) / 256) // 1563
#define PREP_BX 448                              // (3*256*128 + 128*128)/256
#define H2B_BX  6250                             // (50000*256/8)/256

using bf16x8 = __attribute__((ext_vector_type(8))) short;
using f32x4  = __attribute__((ext_vector_type(4))) float;

__device__ __forceinline__ float bf2f(unsigned short u) {
  union { unsigned int i; float f; } x; x.i = ((unsigned int)u) << 16; return x.f;
}
__device__ __forceinline__ unsigned short f2bf(float f) {
  union { float f; unsigned int i; } x; x.f = f;
  unsigned int r = x.i + 0x7fffu + ((x.i >> 16) & 1u);
  return (unsigned short)(r >> 16);
}
__device__ __forceinline__ float tanh_fast(float x) {
  // tanh(x) = 1 - 2/(e^{2x}+1); __expf ~8cyc vs ~40 libm tanhf. |err|~1e-6.
  float e = __expf(2.f * x);
  return 1.f - 2.f / (e + 1.f);
}

// -------- prep: fcwT/w1T transposes (x<PREP_BX) + h -> bf16 (x>=PREP_BX) ------
__global__ __launch_bounds__(256)
void prep_kernel(const float* __restrict__ fcw, const float* __restrict__ w1,
                 const float* __restrict__ h,
                 unsigned short* __restrict__ fcwT, unsigned short* __restrict__ w1T,
                 unsigned short* __restrict__ hb) {
  if (blockIdx.x < PREP_BX) {
    int i = blockIdx.x * 256 + threadIdx.x;
    const int NFC = N_META * IN_DIM * HD;
    if (i < NFC) {
      int p = i / (IN_DIM * HD);
      int rem = i - p * (IN_DIM * HD);
      int k = rem / HD, n = rem - k * HD;
      fcwT[(size_t)p * HD * IN_DIM + n * IN_DIM + k] = f2bf(fcw[i]);
    } else if (i < NFC + HD * HD) {
      int j = i - NFC;
      int k = j / HD, n = j - k * HD;
      w1T[n * HD + k] = f2bf(w1[j]);
    }
  } else {
    size_t j = (size_t)(blockIdx.x - PREP_BX) * 256 + threadIdx.x;  // 8 floats each
    size_t base = j * 8;
    float4 a0 = *(const float4*)(h + base);
    float4 a1 = *(const float4*)(h + base + 4);
    ushort4 u0, u1;
    u0.x = f2bf(a0.x); u0.y = f2bf(a0.y); u0.z = f2bf(a0.z); u0.w = f2bf(a0.w);
    u1.x = f2bf(a1.x); u1.y = f2bf(a1.y); u1.z = f2bf(a1.z); u1.w = f2bf(a1.w);
    *(ushort4*)(hb + base)     = u0;
    *(ushort4*)(hb + base + 4) = u1;
  }
}

// ===== Merged dispatch A: bin (x<NBKT) || gemm_feat (x>=NBKT), y = meta ======
__global__ __launch_bounds__(256)
void bin_gemm_kernel(const int* __restrict__ edges, int* __restrict__ gcur,
                     unsigned int* __restrict__ bktbuf,
                     const unsigned short* __restrict__ HB,  // h bf16 [N,256]
                     const unsigned short* __restrict__ BT,
                     unsigned short* __restrict__ Cb, int nrows) {
  __shared__ char smem[15360];   // gemm: 64*40*2 + 128*40*2; bin: 3*196*4=2352
  int p = blockIdx.y;
  int t = threadIdx.x;
  if (blockIdx.x < NBKT) {
    // ---- bin body: padded-bucket counting-sort pass A ----
    int* hist  = (int*)smem;
    int* gbase = hist + NBKT;
    int* fill  = gbase + NBKT;
    int e0 = blockIdx.x * TILE_E;
    const int* src = edges + (size_t)p * 2 * N_EDGES;
    const int* dst = src + N_EDGES;
    for (int i = t; i < NBKT; i += 256) { hist[i] = 0; fill[i] = 0; }
    __syncthreads();
    for (int i = t; i < TILE_E; i += 256) {
      int e = e0 + i;
      if (e < N_EDGES) atomicAdd(&hist[dst[e] >> 8], 1);
    }
    __syncthreads();
    for (int i = t; i < NBKT; i += 256) {
      int idx = p * NBKT + i;
      gbase[i] = hist[i] ? (idx * BCAP + atomicAdd(&gcur[idx], hist[i])) : 0;
    }
    __syncthreads();
    for (int i = t; i < TILE_E; i += 256) {
      int e = e0 + i;
      if (e < N_EDGES) {
        int d = dst[e];
        int b = d >> 8;
        int r = atomicAdd(&fill[b], 1);
        bktbuf[gbase[b] + r] = ((unsigned int)(d & 255) << 16) | (unsigned int)src[e];
      }
    }
  } else {
    // ---- gemm body: featb[m] = bf16(hb @ fc_w[m]) ----
    unsigned short* As = (unsigned short*)smem;          // 64*40
    unsigned short* Bs = As + 64 * 40;                   // 128*40
    int w = t >> 6, l = t & 63, q = l >> 4, s = l & 15;
    int row0 = (blockIdx.x - NBKT) * 64;
    const unsigned short* BTm = BT + (size_t)p * HD * IN_DIM;
    f32x4 acc[8] = {};
    for (int k0 = 0; k0 < IN_DIM; k0 += 32) {
      {
        int r = t >> 2, c = (t & 3) * 8;
        int gr = row0 + r;
        uint4 a = make_uint4(0, 0, 0, 0);
        if (gr < nrows) a = *(const uint4*)(HB + (size_t)gr * IN_DIM + k0 + c);
        *(uint4*)&As[r * 40 + c] = a;
      }
      {
        int n = t >> 1, c = (t & 1) * 16;
        uint4 b0 = *(const uint4*)(BTm + (size_t)n * IN_DIM + k0 + c);
        uint4 b1 = *(const uint4*)(BTm + (size_t)n * IN_DIM + k0 + c + 8);
        *(uint4*)&Bs[n * 40 + c]     = b0;
        *(uint4*)&Bs[n * 40 + c + 8] = b1;
      }
      __syncthreads();
      bf16x8 af = *(bf16x8*)&As[(w * 16 + s) * 40 + q * 8];
      #pragma unroll
      for (int f = 0; f < 8; ++f) {
        bf16x8 bf = *(bf16x8*)&Bs[(f * 16 + s) * 40 + q * 8];
        acc[f] = __builtin_amdgcn_mfma_f32_16x16x32_bf16(af, bf, acc[f], 0, 0, 0);
      }
      __syncthreads();
    }
    unsigned short* Cm = Cb + (size_t)p * N_NODES * HD;
    #pragma unroll
    for (int f = 0; f < 8; ++f) {
      #pragma unroll
      for (int r = 0; r < 4; ++r) {
        int gr = row0 + w * 16 + q * 4 + r;
        if (gr < nrows) Cm[(size_t)gr * HD + f * 16 + s] = f2bf(acc[f][r]);
      }
    }
  }
}

// ===== Merged dispatch B: csr_sort (x<NBKT) || el_er (x>=NBKT), y = meta =====
__global__ __launch_bounds__(256)
void sort_eler_kernel(const int* __restrict__ gcur,
                      const unsigned int* __restrict__ bktbuf,
                      int* __restrict__ offsB, int* __restrict__ offsE,
                      int* __restrict__ csr,
                      const unsigned short* __restrict__ featb3,
                      const float* __restrict__ al, const float* __restrict__ ar,
                      float* __restrict__ el3, float* __restrict__ er3) {
  __shared__ int lh[256];
  __shared__ int cur[256];
  __shared__ int wsum[4];
  int p = blockIdx.y;
  int t = threadIdx.x;
  if (blockIdx.x < NBKT) {
    // ---- csr_sort body ----
    int b = blockIdx.x;
    int lane = t & 63, wid = t >> 6;
    int idx = p * NBKT + b;
    int S = idx * BCAP;
    int E = S + gcur[idx];
    int node0 = b * 256;
    int nn = min(256, N_NODES - node0);
    int gi0 = p * N_NODES + node0;
    lh[t] = 0;
    __syncthreads();
    for (int i = S + t; i < E; i += 256) atomicAdd(&lh[bktbuf[i] >> 16], 1);
    __syncthreads();
    int v = lh[t];
    int s = v;
    #pragma unroll
    for (int d = 1; d < 64; d <<= 1) {
      int x = __shfl_up(s, d);
      if (lane >= d) s += x;
    }
    if (lane == 63) wsum[wid] = s;
    __syncthreads();
    int woff = 0;
    #pragma unroll
    for (int k = 0; k < 4; ++k) if (k < wid) woff += wsum[k];
    int excl = S + woff + s - v;
    if (t < nn) {
      offsB[gi0 + t] = excl;
      offsE[gi0 + t] = excl + v;
    }
    cur[t] = excl;
    __syncthreads();
    for (int i = S + t; i < E; i += 256) {
      unsigned int rec = bktbuf[i];
      int pos = atomicAdd(&cur[rec >> 16], 1);
      csr[pos] = (int)(rec & 0xffffu);
    }
  } else {
    // ---- el_er body ----
    int i = (blockIdx.x - NBKT) * 256 + t;
    if (i >= N_NODES * HEADS) return;
    int node = i >> 3, hh = i & 7;
    const unsigned short* f =
        featb3 + (size_t)p * N_NODES * HD + (size_t)node * HD + hh * HID;
    uint4 u0 = *(const uint4*)(f);
    uint4 u1 = *(const uint4*)(f + 8);
    unsigned int uu[8] = {u0.x, u0.y, u0.z, u0.w, u1.x, u1.y, u1.z, u1.w};
    const float* alm = al + p * HD + hh * HID;
    const float* arm = ar + p * HD + hh * HID;
    float sl = 0.f, sr = 0.f;
    #pragma unroll
    for (int q = 0; q < 8; ++q) {
      float v0 = __uint_as_float(uu[q] << 16);
      float v1 = __uint_as_float(uu[q] & 0xffff0000u);
      int d = q * 2;
      sl += v0 * alm[d] + v1 * alm[d + 1];
      sr += v0 * arm[d] + v1 * arm[d + 1];
    }
    el3[(size_t)p * N_NODES * HEADS + i] = sl;
    er3[(size_t)p * N_NODES * HEADS + i] = sr;
  }
}

// ------- GAT aggregation (R12 structure), per-meta dispatch -------------------
__global__ __launch_bounds__(256)
void aggregate_kernel(const int* __restrict__ offsB3, const int* __restrict__ offsE3,
                      const int* __restrict__ csr,
                      const uint4* __restrict__ featb3_u4,
                      const float* __restrict__ el3, const float* __restrict__ er3,
                      uint4* __restrict__ zb3_u4, int m) {
  int node = blockIdx.x * 4 + (threadIdx.x >> 6);
  if (node >= N_NODES) return;
  const uint4* featb_u4 = featb3_u4 + (size_t)m * N_NODES * 16;
  const float* el = el3 + (size_t)m * N_NODES * HEADS;
  const float* er = er3 + (size_t)m * N_NODES * HEADS;
  uint4* z_u4 = zb3_u4 + (size_t)m * N_NODES * 16;
  int lane = threadIdx.x & 63;
  int k = lane >> 3, h = lane & 7;   // phase-1 role
  int qg = lane >> 4;                // phase-2 edge sub-slot
  int li = lane & 15;                // phase-2 column quad (cols 8li..8li+7)
  int ch = li >> 1;                  // head of those columns
  int beg = offsB3[m * N_NODES + node], end = offsE3[m * N_NODES + node];
  float erh = er[node * HEADS + h];
  float ssum = 0.f;
  float a[8] = {};
  int i = beg;
  for (; i + 8 <= end; i += 8) {
    int sl = csr[i + k];
    float e = el[sl * HEADS + h] + erh;
    e = e > 0.f ? e : 0.2f * e;
    float ev = __expf(e);
    ssum += ev;
    #pragma unroll
    for (int half = 0; half < 2; ++half) {
      int slot = half * 4 + qg;
      float wv = __shfl(ev, slot * 8 + ch);
      int sk = __shfl(sl, slot * 8);
      uint4 v = featb_u4[(size_t)sk * 16 + li];
      a[0] += wv * __uint_as_float(v.x << 16);
      a[1] += wv * __uint_as_float(v.x & 0xffff0000u);
      a[2] += wv * __uint_as_float(v.y << 16);
      a[3] += wv * __uint_as_float(v.y & 0xffff0000u);
      a[4] += wv * __uint_as_float(v.z << 16);
      a[5] += wv * __uint_as_float(v.z & 0xffff0000u);
      a[6] += wv * __uint_as_float(v.w << 16);
      a[7] += wv * __uint_as_float(v.w & 0xffff0000u);
    }
  }
  if (i < end) {
    int nk = end - i;
    int sl = 0; float ev = 0.f;
    if (k < nk) {
      sl = csr[i + k];
      float e = el[sl * HEADS + h] + erh;
      e = e > 0.f ? e : 0.2f * e;
      ev = __expf(e);
    }
    ssum += ev;
    #pragma unroll
    for (int half = 0; half < 2; ++half) {
      if (half * 4 < nk) {
        int slot = half * 4 + qg;
        float wv = __shfl(ev, slot * 8 + ch);   // 0 for invalid slots
        int sk = __shfl(sl, slot * 8);          // 0 for invalid slots (safe row)
        uint4 v = featb_u4[(size_t)sk * 16 + li];
        a[0] += wv * __uint_as_float(v.x << 16);
        a[1] += wv * __uint_as_float(v.x & 0xffff0000u);
        a[2] += wv * __uint_as_float(v.y << 16);
        a[3] += wv * __uint_as_float(v.y & 0xffff0000u);
        a[4] += wv * __uint_as_float(v.z << 16);
        a[5] += wv * __uint_as_float(v.z & 0xffff0000u);
        a[6] += wv * __uint_as_float(v.w << 16);
        a[7] += wv * __uint_as_float(v.w & 0xffff0000u);
      }
    }
  }
  ssum += __shfl_xor(ssum, 8);
  ssum += __shfl_xor(ssum, 16);
  ssum += __shfl_xor(ssum, 32);
  float st = __shfl(ssum, ch);
  #pragma unroll
  for (int j = 0; j < 8; ++j) {
    a[j] += __shfl_xor(a[j], 16);
    a[j] += __shfl_xor(a[j], 32);
  }
  float inv = (end > beg) ? 1.f / st : 0.f;
  if (qg == 0) {
    uint4 o;
    unsigned int p0, p1;
    #pragma unroll
    for (int j = 0; j < 8; ++j) {
      float z = a[j] * inv;
      z = z > 0.f ? z : expm1f(z);
      a[j] = z;
    }
    p0 = (unsigned int)f2bf(a[0]) | ((unsigned int)f2bf(a[1]) << 16); o.x = p0;
    p1 = (unsigned int)f2bf(a[2]) | ((unsigned int)f2bf(a[3]) << 16); o.y = p1;
    p0 = (unsigned int)f2bf(a[4]) | ((unsigned int)f2bf(a[5]) << 16); o.z = p0;
    p1 = (unsigned int)f2bf(a[6]) | ((unsigned int)f2bf(a[7]) << 16); o.w = p1;
    z_u4[(size_t)node * 16 + li] = o;
  }
}

// ------ MFMA GEMM (blockIdx.y = meta, 256 rows/block) + tanh/w2 + accum -------
__global__ __launch_bounds__(256)
void w_gemm_mfma(const unsigned short* __restrict__ Zb3,   // [3][N,128] bf16
                 const unsigned short* __restrict__ BT,    // w1T [128][128] bf16
                 const float* __restrict__ B1, const float* __restrict__ W2,
                 float* __restrict__ numpad3, int nrows) {
  __shared__ unsigned short Bs[128 * 136];
  __shared__ unsigned short As[64 * 136];
  __shared__ float wrow[64];
  __shared__ float part[4][64][2];
  __shared__ float dpart[4];
  int tid = threadIdx.x;
  int m = blockIdx.y;
  const unsigned short* Zb = Zb3 + (size_t)m * N_NODES * HD;
  float* numpad = numpad3 + (size_t)m * NUMPAD;
  int w = tid >> 6, l = tid & 63, q = l >> 4, s = l & 15;
  {
    int n = tid >> 1, c0 = (tid & 1) * 64;
    #pragma unroll
    for (int j = 0; j < 8; ++j)
      *(uint4*)&Bs[n * 136 + c0 + j * 8] = *(const uint4*)(BT + n * HD + c0 + j * 8);
  }
  float b1v[8], w2v[8];
  #pragma unroll
  for (int f = 0; f < 8; ++f) { b1v[f] = B1[f * 16 + s]; w2v[f] = W2[f * 16 + s]; }
  const unsigned int* Zu = (const unsigned int*)Zb;
  float a0 = 0.f, a1 = 0.f, ld = 0.f;
  for (int t = 0; t < 4; ++t) {
    int row0 = blockIdx.x * 256 + t * 64;
    __syncthreads();
    {
      int r = tid >> 2, c0 = (tid & 3) * 32;
      int gr = row0 + r;
      if (gr < nrows) {
        #pragma unroll
        for (int j = 0; j < 4; ++j)
          *(uint4*)&As[r * 136 + c0 + j * 8] =
              *(const uint4*)(Zb + (size_t)gr * HD + c0 + j * 8);
      } else {
        uint4 z = make_uint4(0, 0, 0, 0);
        #pragma unroll
        for (int j = 0; j < 4; ++j) *(uint4*)&As[r * 136 + c0 + j * 8] = z;
      }
    }
    __syncthreads();
    f32x4 acc[8] = {};
    #pragma unroll
    for (int kc = 0; kc < 4; ++kc) {
      bf16x8 af = *(bf16x8*)&As[(w * 16 + s) * 136 + kc * 32 + q * 8];
      #pragma unroll
      for (int f = 0; f < 8; ++f) {
        bf16x8 bf = *(bf16x8*)&Bs[(f * 16 + s) * 136 + kc * 32 + q * 8];
        acc[f] = __builtin_amdgcn_mfma_f32_16x16x32_bf16(af, bf, acc[f], 0, 0, 0);
      }
    }
    #pragma unroll
    for (int r = 0; r < 4; ++r) {
      float p = 0.f;
      #pragma unroll
      for (int f = 0; f < 8; ++f) p += tanh_fast(acc[f][r] + b1v[f]) * w2v[f];
      p += __shfl_xor(p, 1); p += __shfl_xor(p, 2);
      p += __shfl_xor(p, 4); p += __shfl_xor(p, 8);
      if (s == 0) wrow[w * 16 + q * 4 + r] = p;
    }
    __syncthreads();
    for (int r = w; r < 64; r += 4) {
      int gr = row0 + r;
      if (gr < nrows) {
        float e = __expf(wrow[r]);
        unsigned int v = Zu[(size_t)gr * 64 + l];
        a0 += e * __uint_as_float(v << 16);
        a1 += e * __uint_as_float(v & 0xffff0000u);
        if (l == 0) ld += e;
      }
    }
  }
  part[w][l][0] = a0;
  part[w][l][1] = a1;
  if (l == 0) dpart[w] = ld;
  __syncthreads();
  if (w == 0) {
    float s0 = part[0][l][0] + part[1][l][0] + part[2][l][0] + part[3][l][0];
    float s1 = part[0][l][1] + part[1][l][1] + part[2][l][1] + part[3][l][1];
    atomicAdd(&numpad[(2 * l) * 16], s0);
    atomicAdd(&numpad[(2 * l + 1) * 16], s1);
    if (l == 0)
      atomicAdd(&numpad[128 * 16], dpart[0] + dpart[1] + dpart[2] + dpart[3]);
  }
}

// ---------------- final ------------------------------------------------------
__global__ void final_kernel(const float* __restrict__ numpad,
                             const float* __restrict__ PW, const float* __restrict__ PB,
                             float* __restrict__ out) {
  int t = threadIdx.x;
  if (t >= N_META * OUT_DIM) return;
  int m = t >> 3, o = t & 7;
  const float* np = numpad + m * NUMPAD;
  float inv = 1.0f / np[128 * 16];
  float s = 0.f;
  for (int k = 0; k < HD; ++k) s += np[k * 16] * PW[k * OUT_DIM + o];
  out[t] = s * inv + PB[o];
}

extern "C" void kernel_launch(void* const* d_in, const int* in_sizes, int n_in,
                              void* d_out, int out_size, void* d_ws, size_t ws_size,
                              hipStream_t stream) {
  (void)in_sizes; (void)n_in; (void)out_size; (void)ws_size;
  const float* h     = (const float*)d_in[0];
  const int*   edges = (const int*)d_in[1];
  const float* fcw   = (const float*)d_in[2];
  const float* al    = (const float*)d_in[3];
  const float* ar    = (const float*)d_in[4];
  const float* w1    = (const float*)d_in[5];
  const float* b1    = (const float*)d_in[6];
  const float* w2    = (const float*)d_in[7];
  const float* pw    = (const float*)d_in[8];
  const float* pb    = (const float*)d_in[9];
  float* out = (float*)d_out;

  char* ws = (char*)d_ws;
  size_t off = 0;
  auto alloc = [&](size_t bytes) -> void* {
    void* p = ws + off;
    off = (off + bytes + 255) & ~(size_t)255;
    return p;
  };
  unsigned short* hb     = (unsigned short*)alloc((size_t)N_NODES * IN_DIM * 2);
  unsigned short* featb3 = (unsigned short*)alloc((size_t)N_META * N_NODES * HD * 2);
  unsigned short* zb3    = (unsigned short*)alloc((size_t)N_META * N_NODES * HD * 2);
  unsigned short* fcwT   = (unsigned short*)alloc((size_t)N_META * HD * IN_DIM * 2);
  unsigned short* w1T    = (unsigned short*)alloc((size_t)HD * HD * 2);
  float* el3 = (float*)alloc((size_t)N_META * N_NODES * HEADS * 4);
  float* er3 = (float*)alloc((size_t)N_META * N_NODES * HEADS * 4);
  int* gcur  = (int*)alloc((size_t)N_META * NBKT * 4);
  int* offsB = (int*)alloc((size_t)N_META * N_NODES * 4);
  int* offsE = (int*)alloc((size_t)N_META * N_NODES * 4);
  unsigned int* bktbuf = (unsigned int*)alloc((size_t)N_META * NBKT * BCAP * 4);
  int* csr   = (int*)alloc((size_t)N_META * NBKT * BCAP * 4);
  float* numpad = (float*)alloc((size_t)N_META * NUMPAD * 4);

  hipMemsetAsync(numpad, 0, (size_t)N_META * NUMPAD * 4, stream);
  hipMemsetAsync(gcur, 0, (size_t)N_META * NBKT * 4, stream);

  prep_kernel<<<PREP_BX + H2B_BX, 256, 0, stream>>>(fcw, w1, h, fcwT, w1T, hb);

  // A: bin || gemm_feat (independent)
  dim3 agrid_(NBKT + GEMM_BX, N_META);
  bin_gemm_kernel<<<agrid_, 256, 0, stream>>>(
      edges, gcur, bktbuf, hb, fcwT, featb3, N_NODES);

  // B: csr_sort || el_er (independent)
  dim3 bgrid_(NBKT + ELER_BX, N_META);
  sort_eler_kernel<<<bgrid_, 256, 0, stream>>>(
      gcur, bktbuf, offsB, offsE, csr, featb3, al, ar, el3, er3);

  // aggregate: per-meta dispatches (diagnostic split; same total work)
  for (int m = 0; m < N_META; ++m)
    aggregate_kernel<<<(N_NODES + 3) / 4, 256, 0, stream>>>(
        offsB, offsE, csr, (const uint4*)featb3, el3, er3, (uint4*)zb3, m);

  dim3 wgrid((N_NODES + 255) / 256, N_META);
  w_gemm_mfma<<<wgrid, 256, 0, stream>>>(zb3, w1T, b1, w2, numpad, N_NODES);

  final_kernel<<<1, 64, 0, stream>>>(numpad, pw, pb, out);
}

// Round 18
// 361.467 us; speedup vs baseline: 1.0791x; 1.0791x over previous
//
#include <hip/hip_runtime.h>

#define N_NODES 50000
#define N_EDGES 800000
#define N_META 3
#define IN_DIM 256
#define HD 128
#define HEADS 8
#define HID 16
#define OUT_DIM 8
#define NBKT 196          // ceil(50000/256) coarse buckets; == #4096-edge tiles
#define BCAP 5120         // padded bucket capacity (mean 4096, +16 sigma)
#define TILE_E 4096       // edges per bin block
#define NUMPAD 2064       // per-meta padded accum: 128 cols * 16 floats + den
#define GEMM_BX ((N_NODES + 63) / 64)           // 782
#define ELER_BX ((N_NODES * HEADS + 255) / 256) // 1563

using bf16x8 = __attribute__((ext_vector_type(8))) short;
using f32x4  = __attribute__((ext_vector_type(4))) float;

__device__ __forceinline__ float bf2f(unsigned short u) {
  union { unsigned int i; float f; } x; x.i = ((unsigned int)u) << 16; return x.f;
}
__device__ __forceinline__ unsigned short f2bf(float f) {
  union { float f; unsigned int i; } x; x.f = f;
  unsigned int r = x.i + 0x7fffu + ((x.i >> 16) & 1u);
  return (unsigned short)(r >> 16);
}
__device__ __forceinline__ float tanh_fast(float x) {
  // tanh(x) = 1 - 2/(e^{2x}+1); __expf ~8cyc vs ~40 libm tanhf. |err|~1e-6.
  float e = __expf(2.f * x);
  return 1.f - 2.f / (e + 1.f);
}

// ---------------- prep: fcw -> fcwT bf16 [M][128][256]; w1 -> w1T bf16 [128][128]
__global__ __launch_bounds__(256)
void prep_kernel(const float* __restrict__ fcw, const float* __restrict__ w1,
                 unsigned short* __restrict__ fcwT, unsigned short* __restrict__ w1T) {
  int i = blockIdx.x * 256 + threadIdx.x;
  const int NFC = N_META * IN_DIM * HD;
  if (i < NFC) {
    int p = i / (IN_DIM * HD);
    int rem = i - p * (IN_DIM * HD);
    int k = rem / HD, n = rem - k * HD;
    fcwT[(size_t)p * HD * IN_DIM + n * IN_DIM + k] = f2bf(fcw[i]);
  } else if (i < NFC + HD * HD) {
    int j = i - NFC;
    int k = j / HD, n = j - k * HD;
    w1T[n * HD + k] = f2bf(w1[j]);
  }
}

// ===== Merged dispatch A: bin (x<NBKT) || gemm_feat (x>=NBKT), y = meta ======
__global__ __launch_bounds__(256)
void bin_gemm_kernel(const int* __restrict__ edges, int* __restrict__ gcur,
                     unsigned int* __restrict__ bktbuf,
                     const float* __restrict__ A,
                     const unsigned short* __restrict__ BT,
                     unsigned short* __restrict__ Cb, int nrows) {
  __shared__ char smem[15360];   // gemm: 64*40*2 + 128*40*2; bin: 3*196*4=2352
  int p = blockIdx.y;
  int t = threadIdx.x;
  if (blockIdx.x < NBKT) {
    // ---- bin body: padded-bucket counting-sort pass A ----
    int* hist  = (int*)smem;
    int* gbase = hist + NBKT;
    int* fill  = gbase + NBKT;
    int e0 = blockIdx.x * TILE_E;
    const int* src = edges + (size_t)p * 2 * N_EDGES;
    const int* dst = src + N_EDGES;
    for (int i = t; i < NBKT; i += 256) { hist[i] = 0; fill[i] = 0; }
    __syncthreads();
    for (int i = t; i < TILE_E; i += 256) {
      int e = e0 + i;
      if (e < N_EDGES) atomicAdd(&hist[dst[e] >> 8], 1);
    }
    __syncthreads();
    for (int i = t; i < NBKT; i += 256) {
      int idx = p * NBKT + i;
      gbase[i] = hist[i] ? (idx * BCAP + atomicAdd(&gcur[idx], hist[i])) : 0;
    }
    __syncthreads();
    for (int i = t; i < TILE_E; i += 256) {
      int e = e0 + i;
      if (e < N_EDGES) {
        int d = dst[e];
        int b = d >> 8;
        int r = atomicAdd(&fill[b], 1);
        bktbuf[gbase[b] + r] = ((unsigned int)(d & 255) << 16) | (unsigned int)src[e];
      }
    }
  } else {
    // ---- gemm body: featb[m] = bf16(h @ fc_w[m]) ----
    unsigned short* As = (unsigned short*)smem;          // 64*40
    unsigned short* Bs = As + 64 * 40;                   // 128*40
    int w = t >> 6, l = t & 63, q = l >> 4, s = l & 15;
    int row0 = (blockIdx.x - NBKT) * 64;
    const unsigned short* BTm = BT + (size_t)p * HD * IN_DIM;
    f32x4 acc[8] = {};
    for (int k0 = 0; k0 < IN_DIM; k0 += 32) {
      {
        int r = t >> 2, c = (t & 3) * 8;
        int gr = row0 + r;
        float4 a0, a1;
        if (gr < nrows) {
          a0 = *(const float4*)(A + (size_t)gr * IN_DIM + k0 + c);
          a1 = *(const float4*)(A + (size_t)gr * IN_DIM + k0 + c + 4);
        } else {
          a0 = make_float4(0.f, 0.f, 0.f, 0.f); a1 = a0;
        }
        ushort4 u0, u1;
        u0.x = f2bf(a0.x); u0.y = f2bf(a0.y); u0.z = f2bf(a0.z); u0.w = f2bf(a0.w);
        u1.x = f2bf(a1.x); u1.y = f2bf(a1.y); u1.z = f2bf(a1.z); u1.w = f2bf(a1.w);
        *(ushort4*)&As[r * 40 + c]     = u0;
        *(ushort4*)&As[r * 40 + c + 4] = u1;
      }
      {
        int n = t >> 1, c = (t & 1) * 16;
        uint4 b0 = *(const uint4*)(BTm + (size_t)n * IN_DIM + k0 + c);
        uint4 b1 = *(const uint4*)(BTm + (size_t)n * IN_DIM + k0 + c + 8);
        *(uint4*)&Bs[n * 40 + c]     = b0;
        *(uint4*)&Bs[n * 40 + c + 8] = b1;
      }
      __syncthreads();
      bf16x8 af = *(bf16x8*)&As[(w * 16 + s) * 40 + q * 8];
      #pragma unroll
      for (int f = 0; f < 8; ++f) {
        bf16x8 bf = *(bf16x8*)&Bs[(f * 16 + s) * 40 + q * 8];
        acc[f] = __builtin_amdgcn_mfma_f32_16x16x32_bf16(af, bf, acc[f], 0, 0, 0);
      }
      __syncthreads();
    }
    unsigned short* Cm = Cb + (size_t)p * N_NODES * HD;
    #pragma unroll
    for (int f = 0; f < 8; ++f) {
      #pragma unroll
      for (int r = 0; r < 4; ++r) {
        int gr = row0 + w * 16 + q * 4 + r;
        if (gr < nrows) Cm[(size_t)gr * HD + f * 16 + s] = f2bf(acc[f][r]);
      }
    }
  }
}

// ===== Merged dispatch B: csr_sort (x<NBKT) || el_er (x>=NBKT), y = meta =====
__global__ __launch_bounds__(256)
void sort_eler_kernel(const int* __restrict__ gcur,
                      const unsigned int* __restrict__ bktbuf,
                      int* __restrict__ offsB, int* __restrict__ offsE,
                      int* __restrict__ csr,
                      const unsigned short* __restrict__ featb3,
                      const float* __restrict__ al, const float* __restrict__ ar,
                      float* __restrict__ el3, float* __restrict__ er3) {
  __shared__ int lh[256];
  __shared__ int cur[256];
  __shared__ int wsum[4];
  int p = blockIdx.y;
  int t = threadIdx.x;
  if (blockIdx.x < NBKT) {
    // ---- csr_sort body ----
    int b = blockIdx.x;
    int lane = t & 63, wid = t >> 6;
    int idx = p * NBKT + b;
    int S = idx * BCAP;
    int E = S + gcur[idx];
    int node0 = b * 256;
    int nn = min(256, N_NODES - node0);
    int gi0 = p * N_NODES + node0;
    lh[t] = 0;
    __syncthreads();
    for (int i = S + t; i < E; i += 256) atomicAdd(&lh[bktbuf[i] >> 16], 1);
    __syncthreads();
    int v = lh[t];
    int s = v;
    #pragma unroll
    for (int d = 1; d < 64; d <<= 1) {
      int x = __shfl_up(s, d);
      if (lane >= d) s += x;
    }
    if (lane == 63) wsum[wid] = s;
    __syncthreads();
    int woff = 0;
    #pragma unroll
    for (int k = 0; k < 4; ++k) if (k < wid) woff += wsum[k];
    int excl = S + woff + s - v;
    if (t < nn) {
      offsB[gi0 + t] = excl;
      offsE[gi0 + t] = excl + v;
    }
    cur[t] = excl;
    __syncthreads();
    for (int i = S + t; i < E; i += 256) {
      unsigned int rec = bktbuf[i];
      int pos = atomicAdd(&cur[rec >> 16], 1);
      csr[pos] = (int)(rec & 0xffffu);
    }
  } else {
    // ---- el_er body ----
    int i = (blockIdx.x - NBKT) * 256 + t;
    if (i >= N_NODES * HEADS) return;
    int node = i >> 3, hh = i & 7;
    const unsigned short* f =
        featb3 + (size_t)p * N_NODES * HD + (size_t)node * HD + hh * HID;
    uint4 u0 = *(const uint4*)(f);
    uint4 u1 = *(const uint4*)(f + 8);
    unsigned int uu[8] = {u0.x, u0.y, u0.z, u0.w, u1.x, u1.y, u1.z, u1.w};
    const float* alm = al + p * HD + hh * HID;
    const float* arm = ar + p * HD + hh * HID;
    float sl = 0.f, sr = 0.f;
    #pragma unroll
    for (int q = 0; q < 8; ++q) {
      float v0 = __uint_as_float(uu[q] << 16);
      float v1 = __uint_as_float(uu[q] & 0xffff0000u);
      int d = q * 2;
      sl += v0 * alm[d] + v1 * alm[d + 1];
      sr += v0 * arm[d] + v1 * arm[d + 1];
    }
    el3[(size_t)p * N_NODES * HEADS + i] = sl;
    er3[(size_t)p * N_NODES * HEADS + i] = sr;
  }
}

// ------- GAT aggregation (R12 structure): 4 edge-rows per dwordx4 gather ------
__global__ __launch_bounds__(256)
void aggregate_kernel(const int* __restrict__ offsB3, const int* __restrict__ offsE3,
                      const int* __restrict__ csr,
                      const uint4* __restrict__ featb3_u4,
                      const float* __restrict__ el3, const float* __restrict__ er3,
                      uint4* __restrict__ zb3_u4) {
  int m = blockIdx.y;
  int node = blockIdx.x * 4 + (threadIdx.x >> 6);
  if (node >= N_NODES) return;
  const uint4* featb_u4 = featb3_u4 + (size_t)m * N_NODES * 16;
  const float* el = el3 + (size_t)m * N_NODES * HEADS;
  const float* er = er3 + (size_t)m * N_NODES * HEADS;
  uint4* z_u4 = zb3_u4 + (size_t)m * N_NODES * 16;
  int lane = threadIdx.x & 63;
  int k = lane >> 3, h = lane & 7;   // phase-1 role
  int qg = lane >> 4;                // phase-2 edge sub-slot
  int li = lane & 15;                // phase-2 column quad (cols 8li..8li+7)
  int ch = li >> 1;                  // head of those columns
  int beg = offsB3[m * N_NODES + node], end = offsE3[m * N_NODES + node];
  float erh = er[node * HEADS + h];
  float ssum = 0.f;
  float a[8] = {};
  int i = beg;
  for (; i + 8 <= end; i += 8) {
    int sl = csr[i + k];
    float e = el[sl * HEADS + h] + erh;
    e = e > 0.f ? e : 0.2f * e;
    float ev = __expf(e);
    ssum += ev;
    #pragma unroll
    for (int half = 0; half < 2; ++half) {
      int slot = half * 4 + qg;
      float wv = __shfl(ev, slot * 8 + ch);
      int sk = __shfl(sl, slot * 8);
      uint4 v = featb_u4[(size_t)sk * 16 + li];
      a[0] += wv * __uint_as_float(v.x << 16);
      a[1] += wv * __uint_as_float(v.x & 0xffff0000u);
      a[2] += wv * __uint_as_float(v.y << 16);
      a[3] += wv * __uint_as_float(v.y & 0xffff0000u);
      a[4] += wv * __uint_as_float(v.z << 16);
      a[5] += wv * __uint_as_float(v.z & 0xffff0000u);
      a[6] += wv * __uint_as_float(v.w << 16);
      a[7] += wv * __uint_as_float(v.w & 0xffff0000u);
    }
  }
  if (i < end) {
    int nk = end - i;
    int sl = 0; float ev = 0.f;
    if (k < nk) {
      sl = csr[i + k];
      float e = el[sl * HEADS + h] + erh;
      e = e > 0.f ? e : 0.2f * e;
      ev = __expf(e);
    }
    ssum += ev;
    #pragma unroll
    for (int half = 0; half < 2; ++half) {
      if (half * 4 < nk) {
        int slot = half * 4 + qg;
        float wv = __shfl(ev, slot * 8 + ch);   // 0 for invalid slots
        int sk = __shfl(sl, slot * 8);          // 0 for invalid slots (safe row)
        uint4 v = featb_u4[(size_t)sk * 16 + li];
        a[0] += wv * __uint_as_float(v.x << 16);
        a[1] += wv * __uint_as_float(v.x & 0xffff0000u);
        a[2] += wv * __uint_as_float(v.y << 16);
        a[3] += wv * __uint_as_float(v.y & 0xffff0000u);
        a[4] += wv * __uint_as_float(v.z << 16);
        a[5] += wv * __uint_as_float(v.z & 0xffff0000u);
        a[6] += wv * __uint_as_float(v.w << 16);
        a[7] += wv * __uint_as_float(v.w & 0xffff0000u);
      }
    }
  }
  ssum += __shfl_xor(ssum, 8);
  ssum += __shfl_xor(ssum, 16);
  ssum += __shfl_xor(ssum, 32);
  float st = __shfl(ssum, ch);
  #pragma unroll
  for (int j = 0; j < 8; ++j) {
    a[j] += __shfl_xor(a[j], 16);
    a[j] += __shfl_xor(a[j], 32);
  }
  float inv = (end > beg) ? 1.f / st : 0.f;
  if (qg == 0) {
    uint4 o;
    unsigned int p0, p1;
    #pragma unroll
    for (int j = 0; j < 8; ++j) {
      float z = a[j] * inv;
      z = z > 0.f ? z : expm1f(z);
      a[j] = z;
    }
    p0 = (unsigned int)f2bf(a[0]) | ((unsigned int)f2bf(a[1]) << 16); o.x = p0;
    p1 = (unsigned int)f2bf(a[2]) | ((unsigned int)f2bf(a[3]) << 16); o.y = p1;
    p0 = (unsigned int)f2bf(a[4]) | ((unsigned int)f2bf(a[5]) << 16); o.z = p0;
    p1 = (unsigned int)f2bf(a[6]) | ((unsigned int)f2bf(a[7]) << 16); o.w = p1;
    z_u4[(size_t)node * 16 + li] = o;
  }
}

// ------ MFMA GEMM (blockIdx.y = meta, 256 rows/block) + tanh/w2 + accum -------
__global__ __launch_bounds__(256)
void w_gemm_mfma(const unsigned short* __restrict__ Zb3,   // [3][N,128] bf16
                 const unsigned short* __restrict__ BT,    // w1T [128][128] bf16
                 const float* __restrict__ B1, const float* __restrict__ W2,
                 float* __restrict__ numpad3, int nrows) {
  __shared__ unsigned short Bs[128 * 136];
  __shared__ unsigned short As[64 * 136];
  __shared__ float wrow[64];
  __shared__ float part[4][64][2];
  __shared__ float dpart[4];
  int tid = threadIdx.x;
  int m = blockIdx.y;
  const unsigned short* Zb = Zb3 + (size_t)m * N_NODES * HD;
  float* numpad = numpad3 + (size_t)m * NUMPAD;
  int w = tid >> 6, l = tid & 63, q = l >> 4, s = l & 15;
  {
    int n = tid >> 1, c0 = (tid & 1) * 64;
    #pragma unroll
    for (int j = 0; j < 8; ++j)
      *(uint4*)&Bs[n * 136 + c0 + j * 8] = *(const uint4*)(BT + n * HD + c0 + j * 8);
  }
  float b1v[8], w2v[8];
  #pragma unroll
  for (int f = 0; f < 8; ++f) { b1v[f] = B1[f * 16 + s]; w2v[f] = W2[f * 16 + s]; }
  const unsigned int* Zu = (const unsigned int*)Zb;
  float a0 = 0.f, a1 = 0.f, ld = 0.f;
  for (int t = 0; t < 4; ++t) {
    int row0 = blockIdx.x * 256 + t * 64;
    __syncthreads();
    {
      int r = tid >> 2, c0 = (tid & 3) * 32;
      int gr = row0 + r;
      if (gr < nrows) {
        #pragma unroll
        for (int j = 0; j < 4; ++j)
          *(uint4*)&As[r * 136 + c0 + j * 8] =
              *(const uint4*)(Zb + (size_t)gr * HD + c0 + j * 8);
      } else {
        uint4 z = make_uint4(0, 0, 0, 0);
        #pragma unroll
        for (int j = 0; j < 4; ++j) *(uint4*)&As[r * 136 + c0 + j * 8] = z;
      }
    }
    __syncthreads();
    f32x4 acc[8] = {};
    #pragma unroll
    for (int kc = 0; kc < 4; ++kc) {
      bf16x8 af = *(bf16x8*)&As[(w * 16 + s) * 136 + kc * 32 + q * 8];
      #pragma unroll
      for (int f = 0; f < 8; ++f) {
        bf16x8 bf = *(bf16x8*)&Bs[(f * 16 + s) * 136 + kc * 32 + q * 8];
        acc[f] = __builtin_amdgcn_mfma_f32_16x16x32_bf16(af, bf, acc[f], 0, 0, 0);
      }
    }
    #pragma unroll
    for (int r = 0; r < 4; ++r) {
      float p = 0.f;
      #pragma unroll
      for (int f = 0; f < 8; ++f) p += tanh_fast(acc[f][r] + b1v[f]) * w2v[f];
      p += __shfl_xor(p, 1); p += __shfl_xor(p, 2);
      p += __shfl_xor(p, 4); p += __shfl_xor(p, 8);
      if (s == 0) wrow[w * 16 + q * 4 + r] = p;
    }
    __syncthreads();
    for (int r = w; r < 64; r += 4) {
      int gr = row0 + r;
      if (gr < nrows) {
        float e = __expf(wrow[r]);
        unsigned int v = Zu[(size_t)gr * 64 + l];
        a0 += e * __uint_as_float(v << 16);
        a1 += e * __uint_as_float(v & 0xffff0000u);
        if (l == 0) ld += e;
      }
    }
  }
  part[w][l][0] = a0;
  part[w][l][1] = a1;
  if (l == 0) dpart[w] = ld;
  __syncthreads();
  if (w == 0) {
    float s0 = part[0][l][0] + part[1][l][0] + part[2][l][0] + part[3][l][0];
    float s1 = part[0][l][1] + part[1][l][1] + part[2][l][1] + part[3][l][1];
    atomicAdd(&numpad[(2 * l) * 16], s0);
    atomicAdd(&numpad[(2 * l + 1) * 16], s1);
    if (l == 0)
      atomicAdd(&numpad[128 * 16], dpart[0] + dpart[1] + dpart[2] + dpart[3]);
  }
}

// ---------------- final ------------------------------------------------------
__global__ void final_kernel(const float* __restrict__ numpad,
                             const float* __restrict__ PW, const float* __restrict__ PB,
                             float* __restrict__ out) {
  int t = threadIdx.x;
  if (t >= N_META * OUT_DIM) return;
  int m = t >> 3, o = t & 7;
  const float* np = numpad + m * NUMPAD;
  float inv = 1.0f / np[128 * 16];
  float s = 0.f;
  for (int k = 0; k < HD; ++k) s += np[k * 16] * PW[k * OUT_DIM + o];
  out[t] = s * inv + PB[o];
}

extern "C" void kernel_launch(void* const* d_in, const int* in_sizes, int n_in,
                              void* d_out, int out_size, void* d_ws, size_t ws_size,
                              hipStream_t stream) {
  (void)in_sizes; (void)n_in; (void)out_size; (void)ws_size;
  const float* h     = (const float*)d_in[0];
  const int*   edges = (const int*)d_in[1];
  const float* fcw   = (const float*)d_in[2];
  const float* al    = (const float*)d_in[3];
  const float* ar    = (const float*)d_in[4];
  const float* w1    = (const float*)d_in[5];
  const float* b1    = (const float*)d_in[6];
  const float* w2    = (const float*)d_in[7];
  const float* pw    = (const float*)d_in[8];
  const float* pb    = (const float*)d_in[9];
  float* out = (float*)d_out;

  char* ws = (char*)d_ws;
  size_t off = 0;
  auto alloc = [&](size_t bytes) -> void* {
    void* p = ws + off;
    off = (off + bytes + 255) & ~(size_t)255;
    return p;
  };
  unsigned short* featb3 = (unsigned short*)alloc((size_t)N_META * N_NODES * HD * 2);
  unsigned short* zb3    = (unsigned short*)alloc((size_t)N_META * N_NODES * HD * 2);
  unsigned short* fcwT   = (unsigned short*)alloc((size_t)N_META * HD * IN_DIM * 2);
  unsigned short* w1T    = (unsigned short*)alloc((size_t)HD * HD * 2);
  float* el3 = (float*)alloc((size_t)N_META * N_NODES * HEADS * 4);
  float* er3 = (float*)alloc((size_t)N_META * N_NODES * HEADS * 4);
  int* gcur  = (int*)alloc((size_t)N_META * NBKT * 4);
  int* offsB = (int*)alloc((size_t)N_META * N_NODES * 4);
  int* offsE = (int*)alloc((size_t)N_META * N_NODES * 4);
  unsigned int* bktbuf = (unsigned int*)alloc((size_t)N_META * NBKT * BCAP * 4);
  int* csr   = (int*)alloc((size_t)N_META * NBKT * BCAP * 4);
  float* numpad = (float*)alloc((size_t)N_META * NUMPAD * 4);

  hipMemsetAsync(numpad, 0, (size_t)N_META * NUMPAD * 4, stream);
  hipMemsetAsync(gcur, 0, (size_t)N_META * NBKT * 4, stream);

  prep_kernel<<<(N_META * IN_DIM * HD + HD * HD + 255) / 256, 256, 0, stream>>>(
      fcw, w1, fcwT, w1T);

  // A: bin || gemm_feat (independent)
  dim3 agrid_(NBKT + GEMM_BX, N_META);
  bin_gemm_kernel<<<agrid_, 256, 0, stream>>>(
      edges, gcur, bktbuf, h, fcwT, featb3, N_NODES);

  // B: csr_sort || el_er (independent)
  dim3 bgrid_(NBKT + ELER_BX, N_META);
  sort_eler_kernel<<<bgrid_, 256, 0, stream>>>(
      gcur, bktbuf, offsB, offsE, csr, featb3, al, ar, el3, er3);

  dim3 ggrid((N_NODES + 3) / 4, N_META);
  aggregate_kernel<<<ggrid, 256, 0, stream>>>(
      offsB, offsE, csr, (const uint4*)featb3, el3, er3, (uint4*)zb3);

  dim3 wgrid((N_NODES + 255) / 256, N_META);
  w_gemm_mfma<<<wgrid, 256, 0, stream>>>(zb3, w1T, b1, w2, numpad, N_NODES);

  final_kernel<<<1, 64, 0, stream>>>(numpad, pw, pb, out);
}